// Round 4
// baseline (432.511 us; speedup 1.0000x reference)
//
#include <hip/hip_runtime.h>

#define TT 32768          // tokens
#define HH 2048           // hidden
#define NE 64             // experts
#define TOPK 8

#define W_OFF 0
#define I_OFF (TT * TOPK)                 // 262144
#define P_OFF (2 * TT * TOPK)             // 524288
#define B_OFF (P_OFF + (size_t)TT * NE)   // 2621440

typedef __attribute__((ext_vector_type(8))) short short8;
typedef __attribute__((ext_vector_type(4))) float floatx4;

// Exact truncation split: f = h0 + h1 + h2 + eps, |eps| <~ 2^-22 |f|.
__device__ __forceinline__ void split3(const float4 v, ushort4& o0, ushort4& o1, ushort4& o2)
{
    const float* vf = (const float*)&v;
    ushort* p0 = (ushort*)&o0; ushort* p1 = (ushort*)&o1; ushort* p2 = (ushort*)&o2;
#pragma unroll
    for (int i = 0; i < 4; ++i) {
        float f = vf[i];
        unsigned u0 = __float_as_uint(f);
        float h0 = __uint_as_float(u0 & 0xffff0000u);
        float r1 = f - h0;
        unsigned u1 = __float_as_uint(r1);
        float h1 = __uint_as_float(u1 & 0xffff0000u);
        float r2 = r1 - h1;
        unsigned u2 = __float_as_uint(r2);
        p0[i] = (ushort)(u0 >> 16);
        p1[i] = (ushort)(u1 >> 16);
        p2[i] = (ushort)(u2 >> 16);
    }
}

// ---------------------------------------------------------------------------
// One-time prep: gw (64x2048 f32) -> 3 bf16 split planes in MFMA-fragment
// order. Layout (shorts): [((i*4 + nt)*3 + p)*512 + lane*8 + h] where
// i = kchunk*2 + s, e = nt*16 + (lane&15), g = s*4 + (lane>>4),
// content = plane_p(gw[e][i*32 + (lane>>4)*8 + h]).  768 KB total.
// Step i occupies the contiguous 12288-byte range [i*12288, (i+1)*12288).
// Also zeroes the counts workspace (block 0).
// ---------------------------------------------------------------------------
__global__ void prep_b(const float* __restrict__ gw, ushort* __restrict__ bp,
                       int* __restrict__ counts)
{
    if (blockIdx.x == 0 && threadIdx.x < NE) counts[threadIdx.x] = 0;
    const int n = blockIdx.x * 256 + threadIdx.x;   // 0..16383 = (e, granule)
    const int e = n >> 8;
    const int gr = n & 255;                          // k0 = gr*8
    const int c = gr >> 3, g = gr & 7;
    const int s = g >> 2, lqq = g & 3;
    const int nt = e >> 4, lrr = e & 15;
    const int lane = lqq * 16 + lrr;
    const float4 v0 = *(const float4*)&gw[(size_t)e * HH + gr * 8];
    const float4 v1 = *(const float4*)&gw[(size_t)e * HH + gr * 8 + 4];
    ushort4 p0l, p1l, p2l, p0h, p1h, p2h;
    split3(v0, p0l, p1l, p2l);
    split3(v1, p0h, p1h, p2h);
    const int i = c * 2 + s;
    ushort* base = bp + (size_t)((i * 4 + nt) * 3) * 512 + lane * 8;
    *(ushort4*)(base + 0 * 512)     = p0l;
    *(ushort4*)(base + 0 * 512 + 4) = p0h;
    *(ushort4*)(base + 1 * 512)     = p1l;
    *(ushort4*)(base + 1 * 512 + 4) = p1h;
    *(ushort4*)(base + 2 * 512)     = p2l;
    *(ushort4*)(base + 2 * 512 + 4) = p2h;
}

__device__ __forceinline__ void load_lds16(const void* g, void* l)
{
    __builtin_amdgcn_global_load_lds(
        (const __attribute__((address_space(1))) unsigned int*)g,
        (__attribute__((address_space(3))) unsigned int*)l, 16, 0, 0);
}

// ---------------------------------------------------------------------------
// Fused gate GEMM + epilogue. 4 waves/block, wave = 16 tokens x 64 experts;
// block = 64 tokens x all 64 experts (self-contained -> epilogue fusable).
//
// GEMM: A per-lane in registers (each x element loaded+split exactly once);
// B prepped planes staged block-wide into LDS (global_load_lds, ping-pong).
// T4 counted-vmcnt schedule: per step, pinned vmem issue order
// [stage(i+1) x3, xpref(i+2) x2]; step top does s_waitcnt vmcnt(2) (retires
// stage(i), keeps the x pair in flight) + raw s_barrier. No vmcnt(0) drain
// in the loop -> blocks don't phase-lock-stall. WAR-safe with one barrier:
// each wave's ds_reads complete before its MFMAs (lgkmcnt), which precede
// its barrier arrival; next overwrite of a buffer only lands post-barrier.
//
// Epilogue: acc -> lgs[64][68] (16B-aligned rows), syncthreads, wave 0 runs
// the verified per-thread-token softmax/top-8 (token = lane) from LDS.
// All arithmetic identical to the verified kernels -> outputs bitwise same.
// ---------------------------------------------------------------------------
__global__ __launch_bounds__(256, 2) void gate_fused(
    const float* __restrict__ x, const ushort* __restrict__ bp,
    const float* __restrict__ eb, const float* __restrict__ noise,
    float* __restrict__ out, int* __restrict__ counts)
{
    __shared__ ushort bbuf[2][6144];                 // 2 x 12 KB B buffers
    __shared__ __align__(16) float lgs[64 * 68];     // 17 KB logits stage
    __shared__ float s_eb[NE];
    __shared__ int lc[NE];

    const int tid = threadIdx.x;
    const int lane = tid & 63;
    const int wv = tid >> 6;            // 0..3
    const int lr = lane & 15;
    const int lq = lane >> 4;
    const int tok0 = blockIdx.x * 64;
    const int t = tok0 + wv * 16 + lr;  // this lane's A row

    if (tid < NE) { s_eb[tid] = eb[tid]; lc[tid] = 0; }  // wave-0-private data

    const float* xrow = x + (size_t)t * HH + lq * 8;

    floatx4 accB[4], accS[4];
#pragma unroll
    for (int nt = 0; nt < 4; ++nt) { accB[nt] = (floatx4)0.f; accS[nt] = (floatx4)0.f; }

#define STAGE(buf, step) do {                                              \
        const ushort* gsrc = bp + (size_t)(step) * 6144 + tid * 8;         \
        load_lds16(gsrc,        &bbuf[buf][tid * 8]);                      \
        load_lds16(gsrc + 2048, &bbuf[buf][2048 + tid * 8]);               \
        load_lds16(gsrc + 4096, &bbuf[buf][4096 + tid * 8]);               \
    } while (0)

    union U8 { short8 s8; ushort4 u4[2]; };

#define MFMA_BODY(AL, AH, BUFIDX) do {                                     \
        ushort4 q0l, q1l, q2l, q0h, q1h, q2h;                              \
        split3(AL, q0l, q1l, q2l);                                         \
        split3(AH, q0h, q1h, q2h);                                         \
        U8 a0, a1, a2;                                                     \
        a0.u4[0] = q0l; a0.u4[1] = q0h;                                    \
        a1.u4[0] = q1l; a1.u4[1] = q1h;                                    \
        a2.u4[0] = q2l; a2.u4[1] = q2h;                                    \
        const ushort* bb = &bbuf[BUFIDX][lane * 8];                        \
        _Pragma("unroll")                                                  \
        for (int nt = 0; nt < 4; ++nt) {                                   \
            const short8 b0 = *(const short8*)(bb + (nt * 3 + 0) * 512);   \
            const short8 b1 = *(const short8*)(bb + (nt * 3 + 1) * 512);   \
            const short8 b2 = *(const short8*)(bb + (nt * 3 + 2) * 512);   \
            accB[nt] = __builtin_amdgcn_mfma_f32_16x16x32_bf16(a0.s8, b0, accB[nt], 0, 0, 0); \
            accS[nt] = __builtin_amdgcn_mfma_f32_16x16x32_bf16(a0.s8, b1, accS[nt], 0, 0, 0); \
            accS[nt] = __builtin_amdgcn_mfma_f32_16x16x32_bf16(a1.s8, b0, accS[nt], 0, 0, 0); \
            accS[nt] = __builtin_amdgcn_mfma_f32_16x16x32_bf16(a0.s8, b2, accS[nt], 0, 0, 0); \
            accS[nt] = __builtin_amdgcn_mfma_f32_16x16x32_bf16(a1.s8, b1, accS[nt], 0, 0, 0); \
            accS[nt] = __builtin_amdgcn_mfma_f32_16x16x32_bf16(a2.s8, b0, accS[nt], 0, 0, 0); \
        }                                                                  \
    } while (0)

    // prologue: stage step 0 first (vmem queue: [stage0 x3, x x4])
    STAGE(0, 0);
    __builtin_amdgcn_sched_barrier(0);
    float4 pe_l = *(const float4*)(xrow + 0);
    float4 pe_h = *(const float4*)(xrow + 4);
    float4 po_l = *(const float4*)(xrow + 32);
    float4 po_h = *(const float4*)(xrow + 36);

    for (int i = 0; i < 64; i += 2) {
        // ---------------- even step i ----------------
        asm volatile("s_waitcnt vmcnt(2)" ::: "memory");
        __builtin_amdgcn_s_barrier();
        __builtin_amdgcn_sched_barrier(0);
        STAGE((i + 1) & 1, i + 1);           // i <= 62 -> i+1 <= 63 always
        __builtin_amdgcn_sched_barrier(0);
        {
            const float4 cl = pe_l, ch = pe_h;
            const int ip = (i + 2) & 63;     // wraps harmlessly at tail
            pe_l = *(const float4*)(xrow + ip * 32);
            pe_h = *(const float4*)(xrow + ip * 32 + 4);
            MFMA_BODY(cl, ch, i & 1);
        }
        // ---------------- odd step i+1 ----------------
        asm volatile("s_waitcnt vmcnt(2)" ::: "memory");
        __builtin_amdgcn_s_barrier();
        __builtin_amdgcn_sched_barrier(0);
        if (i + 2 < 64) STAGE((i + 2) & 1, i + 2);
        __builtin_amdgcn_sched_barrier(0);
        {
            const float4 cl = po_l, ch = po_h;
            const int ip = (i + 3) & 63;
            po_l = *(const float4*)(xrow + ip * 32);
            po_h = *(const float4*)(xrow + ip * 32 + 4);
            MFMA_BODY(cl, ch, (i + 1) & 1);
        }
    }

    // C/D layout (verified m89/m91): col = lane&15 (expert), row = quad*4+reg
#pragma unroll
    for (int nt = 0; nt < 4; ++nt)
#pragma unroll
        for (int rg = 0; rg < 4; ++rg)
            lgs[(wv * 16 + lq * 4 + rg) * 68 + nt * 16 + lr] = accB[nt][rg] + accS[nt][rg];
    __syncthreads();

    // ---- epilogue (verified round-1 code, token = lane), wave 0 only ------
    if (wv == 0) {
        const int gt = tok0 + lane;
        const float* nz_row = &noise[(size_t)gt * NE];
        float* probs = out + P_OFF;

        float v[NE];
#pragma unroll
        for (int j = 0; j < 16; ++j) {
            const float4 lg = *(const float4*)&lgs[lane * 68 + 4 * j];
            const float4 nz = *(const float4*)&nz_row[4 * j];
            v[4 * j + 0] = lg.x + nz.x * 0.01f + s_eb[4 * j + 0];
            v[4 * j + 1] = lg.y + nz.y * 0.01f + s_eb[4 * j + 1];
            v[4 * j + 2] = lg.z + nz.z * 0.01f + s_eb[4 * j + 2];
            v[4 * j + 3] = lg.w + nz.w * 0.01f + s_eb[4 * j + 3];
        }

        float m = v[0];
#pragma unroll
        for (int i = 1; i < NE; ++i) m = fmaxf(m, v[i]);

#pragma unroll
        for (int i = 0; i < NE; ++i) v[i] = expf(v[i] - m);

        float tr[32];
#pragma unroll
        for (int i = 0; i < 32; ++i) tr[i] = v[2 * i] + v[2 * i + 1];
#pragma unroll
        for (int i = 0; i < 16; ++i) tr[i] = tr[2 * i] + tr[2 * i + 1];
#pragma unroll
        for (int i = 0; i < 8; ++i) tr[i] = tr[2 * i] + tr[2 * i + 1];
#pragma unroll
        for (int i = 0; i < 4; ++i) tr[i] = tr[2 * i] + tr[2 * i + 1];
#pragma unroll
        for (int i = 0; i < 2; ++i) tr[i] = tr[2 * i] + tr[2 * i + 1];
        const float inv = 1.f / (tr[0] + tr[1]);

#pragma unroll
        for (int i = 0; i < NE; ++i) v[i] = v[i] * inv;   // normalized probs

        float4* prow = (float4*)&probs[(size_t)gt * NE];
#pragma unroll
        for (int j = 0; j < 16; ++j)
            prow[j] = make_float4(v[4 * j + 0], v[4 * j + 1], v[4 * j + 2], v[4 * j + 3]);

        float wq[TOPK];
        int iq[TOPK];
        float wsum = 0.f;
#pragma unroll
        for (int r = 0; r < TOPK; ++r) {
            float bv = v[0]; int bi = 0;
#pragma unroll
            for (int i = 1; i < NE; ++i)
                if (v[i] > bv) { bv = v[i]; bi = i; }
            wsum += bv;
            wq[r] = bv;
            iq[r] = bi;
#pragma unroll
            for (int i = 0; i < NE; ++i)
                if (i == bi) v[i] = -1.f;
        }
        const float winv = 1.f / wsum;

        float4* wrow = (float4*)&out[W_OFF + (size_t)gt * TOPK];
        wrow[0] = make_float4(wq[0] * winv, wq[1] * winv, wq[2] * winv, wq[3] * winv);
        wrow[1] = make_float4(wq[4] * winv, wq[5] * winv, wq[6] * winv, wq[7] * winv);
        float4* irow = (float4*)&out[I_OFF + (size_t)gt * TOPK];
        irow[0] = make_float4((float)iq[0], (float)iq[1], (float)iq[2], (float)iq[3]);
        irow[1] = make_float4((float)iq[4], (float)iq[5], (float)iq[6], (float)iq[7]);

#pragma unroll
        for (int r = 0; r < TOPK; ++r) atomicAdd(&lc[iq[r]], 1);
        {
            const int vv = lc[lane];
            if (vv) atomicAdd(&counts[lane], vv);
        }
    }
#undef STAGE
#undef MFMA_BODY
}

// sign(load - 1/64) computed exactly: counts/2^18 is exact in fp32
__global__ void bias_k(const int* __restrict__ c, const float* __restrict__ eb,
                       float* __restrict__ out)
{
    int e = threadIdx.x;
    if (e < NE) {
        float load = (float)c[e] * (1.0f / 262144.0f);
        float err = load - 0.015625f;
        float sg = (err > 0.f) ? 1.f : ((err < 0.f) ? -1.f : 0.f);
        out[B_OFF + e] = eb[e] - 0.001f * sg;
    }
}

extern "C" void kernel_launch(void* const* d_in, const int* in_sizes, int n_in,
                              void* d_out, int out_size, void* d_ws, size_t ws_size,
                              hipStream_t stream)
{
    const float* x     = (const float*)d_in[0];
    const float* gw    = (const float*)d_in[1];
    const float* eb    = (const float*)d_in[2];
    const float* noise = (const float*)d_in[3];
    float* out = (float*)d_out;
    int* counts = (int*)d_ws;
    ushort* bp = (ushort*)((char*)d_ws + 4096);   // 768 KB prepped B planes

    hipLaunchKernelGGL(prep_b, dim3(64), dim3(256), 0, stream, gw, bp, counts);
    hipLaunchKernelGGL(gate_fused, dim3(TT / 64), dim3(256), 0, stream,
                       x, bp, eb, noise, out, counts);
    hipLaunchKernelGGL(bias_k, dim3(1), dim3(64), 0, stream, counts, eb, out);
}